// Round 9
// baseline (135.751 us; speedup 1.0000x reference)
//
#include <hip/hip_runtime.h>
#include <stdint.h>

// B=2, H=16, L=2048, D=64 causal attention, fp32 in/out.
#define B_ 2
#define H_ 16
#define L_ 2048
#define D_ 64
#define BN 64

typedef __attribute__((ext_vector_type(8)))  _Float16 half8;
typedef __attribute__((ext_vector_type(4)))  _Float16 half4;
typedef __attribute__((ext_vector_type(2)))  _Float16 half2t;
typedef __attribute__((ext_vector_type(4)))  float    f32x4;
typedef __attribute__((ext_vector_type(16))) float    f32x16;

// ROUND-9: r5 skeleton (pair (p,31-p), 4-wave 256-thr block, stage-at-top,
// double-buffered 34.8KB LDS, grid 512 = 2 blocks/CU) with the compute core
// rebuilt on 32x32x16 MFMA.
//
// WHY: r1/r4 (TLP), r5 (desync), r6 (amortize), r7 (cross-tile pipe), r8
// (intra-period ILP) all leave per-unit cost ~2000cyc vs ~400cyc issue ->
// scheduling rearrangements of the SAME instruction stream are exhausted.
// This changes the stream: 4x coarser MFMA grain (8+8+4 MFMAs/tile vs 24-28),
// half the LDS ops (all b64, 2-way = free via stride-68 rows), and a single
// branchless tile body.
//
// Unified 32-row trick: wave's 16 X-rows + 16 Y-rows form one 32-col
// B-operand (col = lane&31; 0-15=X, 16-31=Y). The causal mask kv > q_abs
// (per-lane q_abs) subsumes BOTH diagonals and the "Y inactive" case:
// masked scores -> -1e30 -> exp2 = 0 -> P rows contribute nothing to o/lsq.
//
// Fragment layouts (32x32x16 f16):
//   A(m x k): m = lane&31, k = (lane>>5)*8 + j   [analog of our verified
//             16x16x32 A-layout m=lane&15, k=(lane>>4)*8+j]
//   B(k x n): n = lane&31, k = (lane>>5)*8 + j   [same form, verified via qf]
//   C/D:      col = lane&31, row = (reg&3) + 8*(reg>>2) + 4*(lane>>5)  [m74]
// P redistribution (S^T C-layout -> PV A-layout) = pack pairs to u32 +
// v_permlane32_swap_b32 + per-lane cndmask (8 pk + 8 swap + 8 sel per nb).
// lsq rows share o's C-row mapping -> epilogue is o[reg] * (1/lsq[reg]).
//
// LDS stride 68 halves (136B): fragment reads touch 32 rows; 136B pitch ->
// bank = (2*row + ...) mod 32 -> 2-way (free, m136). 16B-multiple pitches
// would be 8-32-way. All frag reads/writes are 8B-aligned b64.
//
// __launch_bounds__ 2nd arg is MIN BLOCKS PER CU on this hipcc (r3: (512,4)
// capped VGPR at 64 -> spill catastrophe). (256,2) -> cap 256, ~200 live.
// blockIdx decode (i%8 -> XCD assumption): bh = ((i>>3)&3)*8+(i&7).

__device__ inline unsigned pack2(float a, float b) {
    half2t t; t[0] = (_Float16)a; t[1] = (_Float16)b;
    return __builtin_bit_cast(unsigned, t);
}

union U8 { half8 h; half4 q[2]; unsigned u[4]; };
union U4 { half4 h; unsigned u[2]; };

__global__ __launch_bounds__(256, 2) void fa_fwd(
    const float* __restrict__ Q, const float* __restrict__ K,
    const float* __restrict__ V, float* __restrict__ O)
{
    const int i  = blockIdx.x;
    const int bh = ((i >> 3) & 3) * 8 + (i & 7);
    const int p  = i >> 5;               // 0..15
    const int dY = p;                    // short strip diagonal
    const int dX = 31 - p;               // long strip diagonal (>= 16)

    const int tid  = threadIdx.x;
    const int wrow = tid >> 6;           // wave = 16-row band of each strip
    const int lane = tid & 63;
    const int col  = lane & 31;          // unified q column (0-15 X, 16-31 Y)
    const int h    = lane >> 5;
    const int h4   = h * 4;
    const int h8   = h * 8;
    const bool isY  = (col >= 16);
    const bool isH1 = (h == 1);

    const size_t base = (size_t)bh * (size_t)(L_ * D_);
    const float* Qb = Q + base;
    const float* Kb = K + base;
    const float* Vb = V + base;
    float*       Ob = O + base;

    // Double-buffered, stride-68 rows (34,816 B total).
    __shared__ __align__(16) _Float16 Klds[2][BN][68];  // K[kv][d]
    __shared__ __align__(16) _Float16 Vt  [2][D_][68];  // V^T[d][kv]

    // ---- staging (r5 mechanics, new strides) ----
    const int srow  = tid >> 4;          // K: row 0..15 (x4)
    const int scol  = (tid & 15) * 4;    // K: col (halves)
    const int vw    = tid >> 6;          // V: 16-row kv band
    const int vlane = lane;              // V: d = vlane

    float fk[16];
    float fv[16];

    auto prefetch = [&](int kv0) {
        float4* kq = (float4*)fk;
        const float* kp = Kb + (size_t)kv0 * D_ + (size_t)tid * 4;
        #pragma unroll
        for (int u = 0; u < 4; ++u) kq[u] = *(const float4*)(kp + u * 1024);
        const float* vp = Vb + (size_t)(kv0 + vw * 16) * D_ + vlane;
        #pragma unroll
        for (int rr = 0; rr < 16; ++rr) fv[rr] = vp[rr * D_];
    };

    auto stage = [&](int buf) {
        const float4* kq = (const float4*)fk;
        #pragma unroll
        for (int u = 0; u < 4; ++u) {
            U4 w;
            w.u[0] = pack2(kq[u].x, kq[u].y);
            w.u[1] = pack2(kq[u].z, kq[u].w);
            *(half4*)&Klds[buf][u * 16 + srow][scol] = w.h;
        }
        #pragma unroll
        for (int c = 0; c < 4; ++c) {
            U4 w;
            w.u[0] = pack2(fv[4 * c + 0], fv[4 * c + 1]);
            w.u[1] = pack2(fv[4 * c + 2], fv[4 * c + 3]);
            *(half4*)&Vt[buf][vlane][vw * 16 + 4 * c] = w.h;
        }
    };

    // ---- Q fragments (B-operand, cs pre-folded) ----
    const float cs = 0.18033688011112042f; // (1/8) * log2(e)
    const int q_abs = (isY ? dY : dX) * 64 + wrow * 16 + (lane & 15);
    half8 qf[4];
    #pragma unroll
    for (int ds = 0; ds < 4; ++ds) {
        const float* pq = Qb + (size_t)q_abs * D_ + ds * 16 + h8;
        float4 a = *(const float4*)(pq);
        float4 b = *(const float4*)(pq + 4);
        U8 f;
        f.u[0] = pack2(a.x * cs, a.y * cs);
        f.u[1] = pack2(a.z * cs, a.w * cs);
        f.u[2] = pack2(b.x * cs, b.y * cs);
        f.u[3] = pack2(b.z * cs, b.w * cs);
        qf[ds] = f.h;
    }

    f32x16 o0, o1, lsq;
    #pragma unroll
    for (int r = 0; r < 16; ++r) { o0[r] = 0.f; o1[r] = 0.f; lsq[r] = 0.f; }
    half8 onesf;
    #pragma unroll
    for (int j = 0; j < 8; ++j) onesf[j] = (_Float16)1.f;

    // ---- prologue (dX >= 16: tiles 0,1 exist) ----
    prefetch(0);
    stage(0);
    prefetch(BN);
    __syncthreads();

    // ---- main loop ----
    for (int t = 0; t <= dX; ++t) {
        const int buf = t & 1;

        if (t < dX)      stage(buf ^ 1);         // regs prefetched last iter
        if (t + 2 <= dX) prefetch((t + 2) * BN);

        // ---- S^T = K.Q^T : two 32-kv blocks, accumulate over d ----
        f32x16 s0, s1;
        #pragma unroll
        for (int r = 0; r < 16; ++r) { s0[r] = 0.f; s1[r] = 0.f; }
        __builtin_amdgcn_s_setprio(1);
        #pragma unroll
        for (int ds = 0; ds < 4; ++ds) {
            U8 kf0, kf1;
            kf0.q[0] = *(const half4*)&Klds[buf][ 0 + col][ds * 16 + h8];
            kf0.q[1] = *(const half4*)&Klds[buf][ 0 + col][ds * 16 + h8 + 4];
            kf1.q[0] = *(const half4*)&Klds[buf][32 + col][ds * 16 + h8];
            kf1.q[1] = *(const half4*)&Klds[buf][32 + col][ds * 16 + h8 + 4];
            s0 = __builtin_amdgcn_mfma_f32_32x32x16_f16(kf0.h, qf[ds], s0, 0, 0, 0);
            s1 = __builtin_amdgcn_mfma_f32_32x32x16_f16(kf1.h, qf[ds], s1, 0, 0, 0);
        }
        __builtin_amdgcn_s_setprio(0);

        // ---- unified causal mask (covers both diagonals AND Y-inactive) ----
        // kv = t*64 + nb*32 + (reg&3)+8*(reg>>2)+4h ; mask iff kv > q_abs.
        if (t >= dY) {
            const int thr = q_abs - t * 64;
            #pragma unroll
            for (int reg = 0; reg < 16; ++reg) {
                const int cr = (reg & 3) + 8 * (reg >> 2);
                s0[reg] = (cr + h4      > thr) ? -1e30f : s0[reg];
                s1[reg] = (cr + h4 + 32 > thr) ? -1e30f : s1[reg];
            }
        }

        // ---- exp2 -> pack -> permlane32_swap -> PV A-fragments ----
        half8 paf[4];
        #pragma unroll
        for (int nb = 0; nb < 2; ++nb) {
            f32x16 sv = nb ? s1 : s0;
            unsigned pk[8];
            #pragma unroll
            for (int j2 = 0; j2 < 8; ++j2) {
                float e0 = __builtin_amdgcn_exp2f(sv[2 * j2]);
                float e1 = __builtin_amdgcn_exp2f(sv[2 * j2 + 1]);
                pk[j2] = pack2(e0, e1);
            }
            unsigned lo[8], hi[8];
            #pragma unroll
            for (int j2 = 0; j2 < 8; ++j2) {
                unsigned a = pk[j2], b = pk[j2];
                asm("v_permlane32_swap_b32 %0, %1" : "+v"(a), "+v"(b));
                lo[j2] = a;   // [pk@lanes0-31 | pk@lanes0-31]
                hi[j2] = b;   // [pk@lanes32-63 | pk@lanes32-63]
            }
            // A-frag (m=q=lane&31, k=kv_local=(lane>>5)*8+j), per 16-kv slice:
            U8 f0, f1;
            f0.u[0] = isH1 ? lo[2] : pk[0];
            f0.u[1] = isH1 ? lo[3] : pk[1];
            f0.u[2] = isH1 ? pk[2] : hi[0];
            f0.u[3] = isH1 ? pk[3] : hi[1];
            f1.u[0] = isH1 ? lo[6] : pk[4];
            f1.u[1] = isH1 ? lo[7] : pk[5];
            f1.u[2] = isH1 ? pk[6] : hi[4];
            f1.u[3] = isH1 ? pk[7] : hi[5];
            paf[nb * 2 + 0] = f0.h;
            paf[nb * 2 + 1] = f1.h;
        }

        // ---- O += P.V and row-sums (lsq rows == o rows) ----
        __builtin_amdgcn_s_setprio(1);
        #pragma unroll
        for (int ksg = 0; ksg < 4; ++ksg) {
            U8 vf0, vf1;
            vf0.q[0] = *(const half4*)&Vt[buf][ 0 + col][ksg * 16 + h8];
            vf0.q[1] = *(const half4*)&Vt[buf][ 0 + col][ksg * 16 + h8 + 4];
            vf1.q[0] = *(const half4*)&Vt[buf][32 + col][ksg * 16 + h8];
            vf1.q[1] = *(const half4*)&Vt[buf][32 + col][ksg * 16 + h8 + 4];
            o0  = __builtin_amdgcn_mfma_f32_32x32x16_f16(paf[ksg], vf0.h, o0, 0, 0, 0);
            o1  = __builtin_amdgcn_mfma_f32_32x32x16_f16(paf[ksg], vf1.h, o1, 0, 0, 0);
            lsq = __builtin_amdgcn_mfma_f32_32x32x16_f16(paf[ksg], onesf, lsq, 0, 0, 0);
        }
        __builtin_amdgcn_s_setprio(0);

        if (t < dX) __syncthreads();
    }

    // ---- epilogue: normalize (row-aligned) and store ----
    // o/lsq row = (reg&3)+8*(reg>>2)+4h; regs 0-7 -> X rows, 8-15 -> Y rows
    // (compile-time split since (reg&3)+8*(reg>>2) jumps 0..11 / 16..27).
    float linv[16];
    #pragma unroll
    for (int r = 0; r < 16; ++r) linv[r] = 1.0f / lsq[r];
    #pragma unroll
    for (int reg = 0; reg < 16; ++reg) {
        const int cr0 = (reg & 3) + 8 * (reg >> 2);
        const int qg = (cr0 < 16)
            ? dX * 64 + wrow * 16 + cr0 + h4
            : dY * 64 + wrow * 16 + (cr0 - 16) + h4;
        Ob[(size_t)qg * D_ + col]      = o0[reg] * linv[reg];
        Ob[(size_t)qg * D_ + 32 + col] = o1[reg] * linv[reg];
    }
}

extern "C" void kernel_launch(void* const* d_in, const int* in_sizes, int n_in,
                              void* d_out, int out_size, void* d_ws, size_t ws_size,
                              hipStream_t stream) {
    const float* Q = (const float*)d_in[0];
    const float* K = (const float*)d_in[1];
    const float* V = (const float*)d_in[2];
    float*       O = (float*)d_out;
    fa_fwd<<<dim3(16 * B_ * H_), dim3(256), 0, stream>>>(Q, K, V, O);
}